// Round 14
// baseline (325.326 us; speedup 1.0000x reference)
//
#include <hip/hip_runtime.h>
#include <hip/hip_fp16.h>
#include <hip/hip_cooperative_groups.h>
#include <stdint.h>

namespace cg = cooperative_groups;

#define LN_EPS 1e-5f
#define G1 256
#define P3CAP 5632
#define CAPB 6144

typedef __attribute__((ext_vector_type(8))) short s16x8;
typedef __attribute__((ext_vector_type(4))) float f32x4;

__device__ __forceinline__ float b2f(unsigned short u) {
    union { unsigned int i; float f; } v; v.i = ((unsigned int)u) << 16; return v.f;
}
__device__ __forceinline__ unsigned short f2b(float f) {
    union { float f; unsigned int i; } v; v.f = f;
    unsigned int u = v.i;
    return (unsigned short)((u + 0x7fffu + ((u >> 16) & 1u)) >> 16);
}
__device__ __forceinline__ unsigned int pk2(float a, float b) {
    return (unsigned int)f2b(a) | ((unsigned int)f2b(b) << 16);
}
__device__ __forceinline__ __half2 u2h2(unsigned int u) {
    union { unsigned int i; __half2 h; } v; v.i = u; return v.h;
}
__device__ __forceinline__ float rdf(const void* p, int i, int f32flag) {
    return f32flag ? ((const float*)p)[i] : b2f(((const unsigned short*)p)[i]);
}

struct Params {
    const unsigned short* xu;
    const int* ei;
    const void* ew;
    const void* W1; const void* W2;
    const void* b1; const void* b2;
    const void* g1; const void* g2;
    const void* be1; const void* be2;
    unsigned short* Wt1; unsigned short* Wt2;
    float* sm;
    unsigned int* gA;
    unsigned char* g8;
    int* cnt2d; int* lofs2d;
    unsigned int* edata;
    uint2* nfo;
    unsigned short* Hh;
    unsigned short* Hh2;
    void* out;
    int N, E, B, chunk, nodeBlocks, gemmBlocks;
};

// block-local dtype detection (no cross-block dependency)
__device__ __forceinline__ void detect_types(const Params& p, int t, int* scratch,
                                             int& f32f, int& f64) {
    if (t < 2) scratch[t] = 0;
    __syncthreads();
    int c1 = 0;
    for (int i = t; i < 2048; i += 256)
        if (fabsf(b2f(p.xu[i])) > 1e6f) ++c1;
    if (c1) atomicAdd(&scratch[0], c1);
    int mn = (p.E < 1024) ? p.E : 1024;
    int z = 0;
    for (int i = t; i < mn; i += 256)
        if (p.ei[2 * i + 1] == 0) ++z;
    if (z) atomicAdd(&scratch[1], z);
    __syncthreads();
    f32f = (scratch[0] > 32) ? 1 : 0;
    f64  = (scratch[1] > (mn >> 1)) ? 1 : 0;
    __syncthreads();
}

// Phase A, vb in [0,G1): LDS-bin edges by bucket (dst>>8), coalesced writeout
__device__ __forceinline__ void phaseA_bin(const Params& p, int vb, int t,
                                           unsigned char* lds, int f32f, int f64) {
    int* hist = (int*)lds;
    int* cur  = (int*)(lds + 1024);
    int* tmp  = (int*)(lds + 2048);
    unsigned int* bin32 = (unsigned int*)(lds + 3072);
    unsigned char* bin8 = lds + 19456;
    const int E = p.E, B = p.B;
    int base = vb * p.chunk;
    int cnt = E - base; if (cnt > p.chunk) cnt = p.chunk; if (cnt < 0) cnt = 0;
    hist[t] = 0;
    __syncthreads();
    for (int i = t; i < cnt; i += 256) {
        int e = base + i;
        int d = f64 ? p.ei[2 * E + 2 * e] : p.ei[E + e];
        atomicAdd(&hist[d >> 8], 1);
    }
    __syncthreads();
    int v = hist[t];
    tmp[t] = v;
    __syncthreads();
    for (int d = 1; d < 256; d <<= 1) {
        int x = (t >= d) ? tmp[t - d] : 0;
        __syncthreads();
        tmp[t] += x;
        __syncthreads();
    }
    int excl = tmp[t] - v;
    cur[t] = excl;
    if (t < B) { p.cnt2d[t * G1 + vb] = v; p.lofs2d[t * G1 + vb] = excl; }
    __syncthreads();
    for (int i = t; i < cnt; i += 256) {
        int e = base + i;
        int d, sN;
        if (f64) { d = p.ei[2 * E + 2 * e]; sN = p.ei[2 * e]; }
        else     { d = p.ei[E + e];         sN = p.ei[e]; }
        float w = f32f ? ((const float*)p.ew)[e] : b2f(((const unsigned short*)p.ew)[e]);
        __half wh = __float2half(w);
        int pos = atomicAdd(&cur[d >> 8], 1);
        bin32[pos] = (unsigned int)(sN & 0xffff) | ((unsigned int)__half_as_ushort(wh) << 16);
        bin8[pos]  = (unsigned char)(d & 255);
    }
    __syncthreads();
    for (int j = t; j < cnt; j += 256) {
        p.gA[base + j] = bin32[j];
        p.g8[base + j] = bin8[j];
    }
    __syncthreads();
}

// Phase A, vb in [G1,G1+64): W transpose -> bf16 + small param convert
__device__ __forceinline__ void phaseA_prep(const Params& p, int vb, int t, int f32f) {
    int i = (vb - G1) * 256 + t;
    int k = i >> 7, j = i & 127;
    p.Wt1[j * 128 + k] = f2b(rdf(p.W1, i, f32f));
    p.Wt2[j * 128 + k] = f2b(rdf(p.W2, i, f32f));
    if (vb == G1 && t < 128) {
        p.sm[t]       = rdf(p.b1, t, f32f);
        p.sm[128 + t] = rdf(p.b2, t, f32f);
        p.sm[256 + t] = rdf(p.g1, t, f32f);
        p.sm[384 + t] = rdf(p.g2, t, f32f);
        p.sm[512 + t] = rdf(p.be1, t, f32f);
        p.sm[640 + t] = rdf(p.be2, t, f32f);
    }
}

// Phase B, vb in [0,B): per-bucket CSR finalize with direct global scatter
__device__ __forceinline__ void phaseB_p3(const Params& p, int vb, int t,
                                          unsigned char* lds) {
    unsigned int* raw = (unsigned int*)lds;        // 22528 B
    unsigned char* r8 = lds + 22528;               // 5632 B
    int* h    = (int*)(lds + 28160);
    int* tmp  = (int*)(lds + 29184);
    int* scnt = (int*)(lds + 30208);
    const int N = p.N;
    int b = vb;
    int segc = p.cnt2d[b * G1 + t];
    int sbase = t * p.chunk + p.lofs2d[b * G1 + t];
    int v = segc;
    tmp[t] = v;
    __syncthreads();
    for (int d = 1; d < 256; d <<= 1) {
        int x = (t >= d) ? tmp[t - d] : 0;
        __syncthreads();
        tmp[t] += x;
        __syncthreads();
    }
    int lo = tmp[t] - v;
    if (t == 255) scnt[0] = tmp[255];
    int j = 0;
    for (; j + 3 < segc; j += 4) {
        unsigned int a0 = p.gA[sbase + j], a1 = p.gA[sbase + j + 1];
        unsigned int a2 = p.gA[sbase + j + 2], a3 = p.gA[sbase + j + 3];
        unsigned char c0 = p.g8[sbase + j], c1 = p.g8[sbase + j + 1];
        unsigned char c2 = p.g8[sbase + j + 2], c3 = p.g8[sbase + j + 3];
        int i0 = lo + j;
        if (i0 + 3 < P3CAP) {
            raw[i0] = a0; raw[i0 + 1] = a1; raw[i0 + 2] = a2; raw[i0 + 3] = a3;
            r8[i0] = c0; r8[i0 + 1] = c1; r8[i0 + 2] = c2; r8[i0 + 3] = c3;
        }
    }
    for (; j < segc; ++j) {
        int idx = lo + j;
        if (idx < P3CAP) { raw[idx] = p.gA[sbase + j]; r8[idx] = p.g8[sbase + j]; }
    }
    h[t] = 0;
    __syncthreads();
    int cnt = scnt[0]; if (cnt > P3CAP) cnt = P3CAP;
    for (int i = t; i < cnt; i += 256) atomicAdd(&h[r8[i]], 1);
    __syncthreads();
    int deg = h[t];
    int pd = (deg + 7) & ~7;
    tmp[t] = pd;
    __syncthreads();
    for (int d = 1; d < 256; d <<= 1) {
        int x = (t >= d) ? tmp[t - d] : 0;
        __syncthreads();
        tmp[t] += x;
        __syncthreads();
    }
    int pexcl = tmp[t] - pd;
    int padTot = tmp[255]; if (padTot > CAPB) padTot = CAPB;
    int node0 = b << 8;
    int gbase = b * CAPB;
    if (node0 + t < N) p.nfo[node0 + t] = make_uint2((unsigned)(gbase + pexcl), (unsigned)deg);
    h[t] = pexcl;
    for (int i = t; i < padTot; i += 256) p.edata[gbase + i] = 0;
    __syncthreads();
    for (int i = t; i < cnt; i += 256) {
        int pos = atomicAdd(&h[r8[i]], 1);
        if (pos < CAPB) p.edata[gbase + pos] = raw[i];
    }
    __syncthreads();
}

// Phase B, vb >= B: layer-1 GEMM (X staged in LDS, W frags from global/L2)
__device__ __forceinline__ void phaseB_gemm1(const Params& p, int vb, int t,
                                             unsigned char* lds, int f32f) {
    unsigned char* xs = lds;
    const int N = p.N;
    int node0 = (vb - p.B) * 64;
#pragma unroll
    for (int it = 0; it < 4; ++it) {
        int c = t + it * 256;
        int row = c >> 4, cc = c & 15;
        int gg = node0 + row;
        uint4 v = make_uint4(0, 0, 0, 0);
        if (gg < N) {
            if (f32f) {
                const float* xr = (const float*)p.xu + (size_t)gg * 128 + cc * 8;
                float4 f0 = *(const float4*)xr;
                float4 f1 = *(const float4*)(xr + 4);
                v.x = pk2(f0.x, f0.y); v.y = pk2(f0.z, f0.w);
                v.z = pk2(f1.x, f1.y); v.w = pk2(f1.z, f1.w);
            } else {
                v = *(const uint4*)((const unsigned short*)p.xu + (size_t)gg * 128 + cc * 8);
            }
        }
        int off = (row * 256 + cc * 16) ^ ((row & 7) << 4);
        *(uint4*)(xs + off) = v;
    }
    __syncthreads();
    int w = t >> 6, l = t & 63;
    int arow = l & 15;
    int apart = l >> 4;
    f32x4 acc[8];
#pragma unroll
    for (int ct = 0; ct < 8; ++ct) acc[ct] = (f32x4){0.f, 0.f, 0.f, 0.f};
#pragma unroll
    for (int ks = 0; ks < 4; ++ks) {
        int grow = w * 16 + arow;
        int aoff = (grow * 256 + ks * 64 + apart * 16) ^ ((grow & 7) << 4);
        s16x8 afrag = *(const s16x8*)(xs + aoff);
#pragma unroll
        for (int ct = 0; ct < 8; ++ct) {
            s16x8 bfrag = *(const s16x8*)(p.Wt1 + (ct * 16 + arow) * 128 + ks * 32 + apart * 8);
            acc[ct] = __builtin_amdgcn_mfma_f32_16x16x32_bf16(afrag, bfrag, acc[ct], 0, 0, 0);
        }
    }
    int orow0 = node0 + w * 16 + apart * 4;
#pragma unroll
    for (int ct = 0; ct < 8; ++ct) {
#pragma unroll
        for (int r = 0; r < 4; ++r) {
            int gg = orow0 + r;
            if (gg < N) {
                __half hh = __float2half(acc[ct][r]);
                p.Hh[(size_t)gg * 128 + ct * 16 + arow] = __half_as_ushort(hh);
            }
        }
    }
    __syncthreads();
}

// per-node aggregate + LN + ReLU
__device__ __forceinline__ uint4 agg_ln_row(const unsigned short* __restrict__ Hs,
                                            const unsigned int* __restrict__ edata,
                                            const uint2* __restrict__ nfo,
                                            const float* __restrict__ bias,
                                            const float* __restrict__ gam,
                                            const float* __restrict__ bet,
                                            int node, int l16, float* r) {
    uint2 info = nfo[node];
    int base = (int)info.x, deg = (int)info.y;
    __half2 a01 = u2h2(0u), a23 = u2h2(0u), a45 = u2h2(0u), a67 = u2h2(0u);
    const uint4* Hl = (const uint4*)Hs + l16;
    for (int b0 = 0; b0 < deg; b0 += 8) {
        const uint4* ep = (const uint4*)(edata + base + b0);
        uint4 q0 = ep[0], q1 = ep[1];
        uint4 h0 = Hl[(size_t)(q0.x & 0xffffu) << 4];
        uint4 h1 = Hl[(size_t)(q0.y & 0xffffu) << 4];
        uint4 h2 = Hl[(size_t)(q0.z & 0xffffu) << 4];
        uint4 h3 = Hl[(size_t)(q0.w & 0xffffu) << 4];
        uint4 h4 = Hl[(size_t)(q1.x & 0xffffu) << 4];
        uint4 h5 = Hl[(size_t)(q1.y & 0xffffu) << 4];
        uint4 h6 = Hl[(size_t)(q1.z & 0xffffu) << 4];
        uint4 h7 = Hl[(size_t)(q1.w & 0xffffu) << 4];
        unsigned int wb; __half2 w2;
#define ACC8(hh, wsrc)                                                        \
        wb = (wsrc) >> 16; w2 = u2h2(wb | (wb << 16));                        \
        a01 = __hfma2(u2h2(hh.x), w2, a01); a23 = __hfma2(u2h2(hh.y), w2, a23); \
        a45 = __hfma2(u2h2(hh.z), w2, a45); a67 = __hfma2(u2h2(hh.w), w2, a67);
        ACC8(h0, q0.x) ACC8(h1, q0.y) ACC8(h2, q0.z) ACC8(h3, q0.w)
        ACC8(h4, q1.x) ACC8(h5, q1.y) ACC8(h6, q1.z) ACC8(h7, q1.w)
#undef ACC8
    }
    float4 bv0 = ((const float4*)bias)[2 * l16];
    float4 bv1 = ((const float4*)bias)[2 * l16 + 1];
    float a0 = __low2float(a01) + bv0.x, a1 = __high2float(a01) + bv0.y;
    float a2 = __low2float(a23) + bv0.z, a3 = __high2float(a23) + bv0.w;
    float a4 = __low2float(a45) + bv1.x, a5 = __high2float(a45) + bv1.y;
    float a6 = __low2float(a67) + bv1.z, a7 = __high2float(a67) + bv1.w;
    float s = ((a0 + a1) + (a2 + a3)) + ((a4 + a5) + (a6 + a7));
#pragma unroll
    for (int m = 8; m >= 1; m >>= 1) s += __shfl_xor(s, m, 64);
    float mu = s * (1.f / 128.f);
    float d0 = a0 - mu, d1 = a1 - mu, d2 = a2 - mu, d3 = a3 - mu;
    float d4 = a4 - mu, d5 = a5 - mu, d6 = a6 - mu, d7 = a7 - mu;
    float q = ((d0 * d0 + d1 * d1) + (d2 * d2 + d3 * d3)) +
              ((d4 * d4 + d5 * d5) + (d6 * d6 + d7 * d7));
#pragma unroll
    for (int m = 8; m >= 1; m >>= 1) q += __shfl_xor(q, m, 64);
    float rs = rsqrtf(q * (1.f / 128.f) + LN_EPS);
    float4 gv0 = ((const float4*)gam)[2 * l16], gv1 = ((const float4*)gam)[2 * l16 + 1];
    float4 bev0 = ((const float4*)bet)[2 * l16], bev1 = ((const float4*)bet)[2 * l16 + 1];
    r[0] = fmaxf(d0 * rs * gv0.x + bev0.x, 0.f);
    r[1] = fmaxf(d1 * rs * gv0.y + bev0.y, 0.f);
    r[2] = fmaxf(d2 * rs * gv0.z + bev0.z, 0.f);
    r[3] = fmaxf(d3 * rs * gv0.w + bev0.w, 0.f);
    r[4] = fmaxf(d4 * rs * gv1.x + bev1.x, 0.f);
    r[5] = fmaxf(d5 * rs * gv1.y + bev1.y, 0.f);
    r[6] = fmaxf(d6 * rs * gv1.z + bev1.z, 0.f);
    r[7] = fmaxf(d7 * rs * gv1.w + bev1.w, 0.f);
    uint4 o;
    o.x = pk2(r[0], r[1]); o.y = pk2(r[2], r[3]);
    o.z = pk2(r[4], r[5]); o.w = pk2(r[6], r[7]);
    return o;
}

// Phase C: agg1 + LN + ReLU + layer-2 GEMM (16 nodes per vb)
__device__ __forceinline__ void phaseC(const Params& p, int vb, int t,
                                       unsigned char* lds) {
    unsigned char* xs = lds;   // 4 KB
    const float* b1f  = p.sm;
    const float* g1f  = p.sm + 256;
    const float* be1f = p.sm + 512;
    const int N = p.N;
    int l16 = t & 15;
    int nodeLocal = t >> 4;
    int node0 = vb * 16;
    int node = node0 + nodeLocal;
    uint4 xv = make_uint4(0, 0, 0, 0);
    float rr[8];
    if (node < N)
        xv = agg_ln_row(p.Hh, p.edata, p.nfo, b1f, g1f, be1f, node, l16, rr);
    __syncthreads();
    {
        int off = (nodeLocal * 256 + l16 * 16) ^ ((nodeLocal & 7) << 4);
        *(uint4*)(xs + off) = xv;
    }
    __syncthreads();
    int w = t >> 6, l = t & 63;
    int arow = l & 15;
    int apart = l >> 4;
    f32x4 acc0 = (f32x4){0.f, 0.f, 0.f, 0.f};
    f32x4 acc1 = (f32x4){0.f, 0.f, 0.f, 0.f};
#pragma unroll
    for (int ks = 0; ks < 4; ++ks) {
        int aoff = (arow * 256 + ks * 64 + apart * 16) ^ ((arow & 7) << 4);
        s16x8 afrag = *(const s16x8*)(xs + aoff);
        s16x8 bf0 = *(const s16x8*)(p.Wt2 + ((w * 2 + 0) * 16 + arow) * 128 + ks * 32 + apart * 8);
        s16x8 bf1 = *(const s16x8*)(p.Wt2 + ((w * 2 + 1) * 16 + arow) * 128 + ks * 32 + apart * 8);
        acc0 = __builtin_amdgcn_mfma_f32_16x16x32_bf16(afrag, bf0, acc0, 0, 0, 0);
        acc1 = __builtin_amdgcn_mfma_f32_16x16x32_bf16(afrag, bf1, acc1, 0, 0, 0);
    }
    int orow0 = node0 + apart * 4;
#pragma unroll
    for (int r = 0; r < 4; ++r) {
        int gg = orow0 + r;
        if (gg < N) {
            __half h0 = __float2half(acc0[r]);
            __half h1 = __float2half(acc1[r]);
            p.Hh2[(size_t)gg * 128 + (w * 2 + 0) * 16 + arow] = __half_as_ushort(h0);
            p.Hh2[(size_t)gg * 128 + (w * 2 + 1) * 16 + arow] = __half_as_ushort(h1);
        }
    }
}

// Phase D: agg2 + LN + ReLU -> out
__device__ __forceinline__ void phaseD(const Params& p, int vb, int t, int f32f) {
    const float* b2f_ = p.sm + 128;
    const float* g2f  = p.sm + 384;
    const float* be2f = p.sm + 640;
    int l16 = t & 15;
    int node = vb * 16 + (t >> 4);
    if (node >= p.N) return;
    float rr[8];
    uint4 o = agg_ln_row(p.Hh2, p.edata, p.nfo, b2f_, g2f, be2f, node, l16, rr);
    if (f32f) {
        float4* op = (float4*)p.out + (size_t)node * 32 + 2 * l16;
        op[0] = make_float4(rr[0], rr[1], rr[2], rr[3]);
        op[1] = make_float4(rr[4], rr[5], rr[6], rr[7]);
    } else {
        ((uint4*)p.out)[(size_t)node * 16 + l16] = o;
    }
}

// ================= cooperative mega-kernel =================
__global__ __launch_bounds__(256, 4) void k_fused(Params p) {
    cg::grid_group grid = cg::this_grid();
    __shared__ __align__(16) unsigned char lds[30720];
    int t = threadIdx.x;
    int f32f, f64;
    detect_types(p, t, (int*)lds, f32f, f64);

    for (int vb = blockIdx.x; vb < G1 + 64; vb += gridDim.x) {
        if (vb >= G1) phaseA_prep(p, vb, t, f32f);
        else          phaseA_bin(p, vb, t, lds, f32f, f64);
    }
    grid.sync();
    for (int vb = blockIdx.x; vb < p.B + p.gemmBlocks; vb += gridDim.x) {
        if (vb < p.B) phaseB_p3(p, vb, t, lds);
        else          phaseB_gemm1(p, vb, t, lds, f32f);
    }
    grid.sync();
    for (int vb = blockIdx.x; vb < p.nodeBlocks; vb += gridDim.x)
        phaseC(p, vb, t, lds);
    grid.sync();
    for (int vb = blockIdx.x; vb < p.nodeBlocks; vb += gridDim.x)
        phaseD(p, vb, t, f32f);
}

// ================= fallback kernels (round-12 pipeline) =================
__global__ __launch_bounds__(256) void k_fA(Params p) {
    __shared__ __align__(16) unsigned char lds[23552];
    int t = threadIdx.x, vb = blockIdx.x;
    int f32f, f64;
    detect_types(p, t, (int*)lds, f32f, f64);
    if (vb >= G1) phaseA_prep(p, vb, t, f32f);
    else          phaseA_bin(p, vb, t, lds, f32f, f64);
}
__global__ __launch_bounds__(256) void k_fB(Params p) {
    __shared__ __align__(16) unsigned char lds[30720];
    int t = threadIdx.x, vb = blockIdx.x;
    int f32f, f64;
    detect_types(p, t, (int*)lds, f32f, f64);
    if (vb < p.B) phaseB_p3(p, vb, t, lds);
    else          phaseB_gemm1(p, vb, t, lds, f32f);
}
__global__ __launch_bounds__(256) void k_fC(Params p) {
    __shared__ __align__(16) unsigned char lds[4096];
    int t = threadIdx.x;
    phaseC(p, blockIdx.x, t, lds);
}
__global__ __launch_bounds__(256) void k_fD(Params p) {
    __shared__ __align__(16) unsigned char lds[64];
    int t = threadIdx.x;
    int f32f, f64;
    detect_types(p, t, (int*)lds, f32f, f64);
    phaseD(p, blockIdx.x, t, f32f);
}

extern "C" void kernel_launch(void* const* d_in, const int* in_sizes, int n_in,
                              void* d_out, int out_size, void* d_ws, size_t ws_size,
                              hipStream_t stream) {
    const int N = in_sizes[0] / 128;
    const int E = in_sizes[2];
    const int B = (N + 255) >> 8;
    const int chunk = (E + G1 - 1) / G1;

    unsigned short* Hh2 = (unsigned short*)d_ws;
    unsigned short* Hh  = Hh2 + (size_t)N * 128;
    unsigned int* gA    = (unsigned int*)(Hh + (size_t)N * 128);
    unsigned int* edata = gA + E;
    unsigned char* g8   = (unsigned char*)(edata + (size_t)B * CAPB);
    int* cnt2d  = (int*)(g8 + ((E + 3) & ~3));
    int* lofs2d = cnt2d + 65536;
    uint2* nfo  = (uint2*)(lofs2d + 65536);
    unsigned short* Wt1 = (unsigned short*)(nfo + N);
    unsigned short* Wt2 = Wt1 + 16384;
    float* sm   = (float*)(Wt2 + 16384);

    Params prm;
    prm.xu = (const unsigned short*)d_in[0];
    prm.ei = (const int*)d_in[1];
    prm.ew = d_in[2];
    prm.W1 = d_in[3]; prm.W2 = d_in[5];
    prm.b1 = d_in[4]; prm.b2 = d_in[6];
    prm.g1 = d_in[7]; prm.g2 = d_in[9];
    prm.be1 = d_in[8]; prm.be2 = d_in[10];
    prm.Wt1 = Wt1; prm.Wt2 = Wt2; prm.sm = sm;
    prm.gA = gA; prm.g8 = g8;
    prm.cnt2d = cnt2d; prm.lofs2d = lofs2d;
    prm.edata = edata; prm.nfo = nfo;
    prm.Hh = Hh; prm.Hh2 = Hh2;
    prm.out = d_out;
    prm.N = N; prm.E = E; prm.B = B; prm.chunk = chunk;
    prm.nodeBlocks = (N + 15) / 16;
    prm.gemmBlocks = (N + 63) / 64;

    // ---- try cooperative mega-kernel with occupancy-derived grid ----
    bool launched = false;
    int coop = 0, dev = 0;
    hipGetDevice(&dev);
    hipDeviceGetAttribute(&coop, hipDeviceAttributeCooperativeLaunch, dev);
    if (coop) {
        int numCU = 0;
        hipDeviceGetAttribute(&numCU, hipDeviceAttributeMultiprocessorCount, dev);
        int occ = 0;
        hipError_t oe = hipOccupancyMaxActiveBlocksPerMultiprocessor(&occ, k_fused, 256, 0);
        if (oe == hipSuccess && occ > 0 && numCU > 0) {
            int grid = occ * numCU;
            if (grid > 2048) grid = 2048;
            void* args[] = { &prm };
            hipError_t le = hipLaunchCooperativeKernel((void*)k_fused, dim3(grid),
                                                       dim3(256), args, 0, stream);
            launched = (le == hipSuccess);
        }
    }
    if (!launched) {
        k_fA<<<G1 + 64, 256, 0, stream>>>(prm);
        k_fB<<<B + prm.gemmBlocks, 256, 0, stream>>>(prm);
        k_fC<<<prm.nodeBlocks, 256, 0, stream>>>(prm);
        k_fD<<<prm.nodeBlocks, 256, 0, stream>>>(prm);
    }
}

// Round 15
// 100.392 us; speedup vs baseline: 3.2406x; 3.2406x over previous
//
#include <hip/hip_runtime.h>
#include <hip/hip_fp16.h>
#include <stdint.h>

#define LN_EPS 1e-5f
#define G1 256
#define P3CAP 6144
#define CAPB 6144

typedef __attribute__((ext_vector_type(8))) short s16x8;
typedef __attribute__((ext_vector_type(4))) float f32x4;

__device__ __forceinline__ float b2f(unsigned short u) {
    union { unsigned int i; float f; } v; v.i = ((unsigned int)u) << 16; return v.f;
}
__device__ __forceinline__ unsigned short f2b(float f) {
    union { float f; unsigned int i; } v; v.f = f;
    unsigned int u = v.i;
    return (unsigned short)((u + 0x7fffu + ((u >> 16) & 1u)) >> 16);
}
__device__ __forceinline__ unsigned int pk2(float a, float b) {
    return (unsigned int)f2b(a) | ((unsigned int)f2b(b) << 16);
}
__device__ __forceinline__ __half2 u2h2(unsigned int u) {
    union { unsigned int i; __half2 h; } v; v.i = u; return v.h;
}
__device__ __forceinline__ float rdf(const void* p, int i, int f32flag) {
    return f32flag ? ((const float*)p)[i] : b2f(((const unsigned short*)p)[i]);
}

// pass 1 (320 blocks): blocks [0,256) bin edges by bucket (dst>>8);
// blocks [256,320) transpose W1/W2 -> bf16 and convert small params.
__global__ __launch_bounds__(256) void k_p1(const unsigned short* __restrict__ xu,
                                            const int* __restrict__ ei, const void* __restrict__ ew,
                                            const void* W1, const void* W2,
                                            const void* b1, const void* b2_,
                                            const void* g1, const void* g2,
                                            const void* be1, const void* be2,
                                            unsigned short* __restrict__ Wt1,
                                            unsigned short* __restrict__ Wt2,
                                            float* __restrict__ sm,
                                            int E, int B, int chunk,
                                            unsigned int* __restrict__ gA,
                                            unsigned char* __restrict__ g8,
                                            int* __restrict__ cnt2d, int* __restrict__ lofs2d,
                                            int* __restrict__ flags) {
    __shared__ int hist[256], cur[256], tmp[256];
    __shared__ unsigned int bin32[4096];
    __shared__ unsigned char bin8[4096];
    int t = threadIdx.x, g = blockIdx.x;
    // ---- local dtype detection ----
    if (t < 2) hist[t] = 0;
    __syncthreads();
    int c1 = 0;
    for (int i = t; i < 2048; i += 256)
        if (fabsf(b2f(xu[i])) > 1e6f) ++c1;
    if (c1) atomicAdd(&hist[0], c1);
    int mn = (E < 1024) ? E : 1024;
    int z = 0;
    for (int i = t; i < mn; i += 256)
        if (ei[2 * i + 1] == 0) ++z;
    if (z) atomicAdd(&hist[1], z);
    __syncthreads();
    int f32f = (hist[0] > 32) ? 1 : 0;
    int f64  = (hist[1] > (mn >> 1)) ? 1 : 0;
    if (g == 0 && t == 0) { flags[0] = f32f; flags[1] = f64; }

    if (g >= G1) {
        int i = (g - G1) * 256 + t;      // 64*256 = 16384
        int k = i >> 7, j = i & 127;
        Wt1[j * 128 + k] = f2b(rdf(W1, i, f32f));
        Wt2[j * 128 + k] = f2b(rdf(W2, i, f32f));
        if (g == G1 && t < 128) {
            sm[t]       = rdf(b1, t, f32f);
            sm[128 + t] = rdf(b2_, t, f32f);
            sm[256 + t] = rdf(g1, t, f32f);
            sm[384 + t] = rdf(g2, t, f32f);
            sm[512 + t] = rdf(be1, t, f32f);
            sm[640 + t] = rdf(be2, t, f32f);
        }
        return;
    }
    __syncthreads();
    // ---- binning ----
    int base = g * chunk;
    int cnt = E - base; if (cnt > chunk) cnt = chunk; if (cnt < 0) cnt = 0;
    hist[t] = 0;
    __syncthreads();
    for (int i = t; i < cnt; i += 256) {
        int e = base + i;
        int d = f64 ? ei[2 * E + 2 * e] : ei[E + e];
        atomicAdd(&hist[d >> 8], 1);
    }
    __syncthreads();
    int v = hist[t];
    tmp[t] = v;
    __syncthreads();
    for (int d = 1; d < 256; d <<= 1) {
        int x = (t >= d) ? tmp[t - d] : 0;
        __syncthreads();
        tmp[t] += x;
        __syncthreads();
    }
    int excl = tmp[t] - v;
    cur[t] = excl;
    if (t < B) { cnt2d[t * G1 + g] = v; lofs2d[t * G1 + g] = excl; }
    __syncthreads();
    for (int i = t; i < cnt; i += 256) {
        int e = base + i;
        int d, sN;
        if (f64) { d = ei[2 * E + 2 * e]; sN = ei[2 * e]; }
        else     { d = ei[E + e];         sN = ei[e]; }
        float w = f32f ? ((const float*)ew)[e] : b2f(((const unsigned short*)ew)[e]);
        __half wh = __float2half(w);
        int p = atomicAdd(&cur[d >> 8], 1);
        bin32[p] = (unsigned int)(sN & 0xffff) | ((unsigned int)__half_as_ushort(wh) << 16);
        bin8[p]  = (unsigned char)(d & 255);
    }
    __syncthreads();
    for (int j = t; j < cnt; j += 256) {
        gA[base + j] = bin32[j];
        g8[base + j] = bin8[j];
    }
}

// dual-role kernel: blocks [0,B) = pass-3 CSR finalize (direct global scatter);
// blocks [B, B+gemmBlocks) = layer-1 MFMA GEMM.
__global__ __launch_bounds__(256) void k_p3g(const unsigned int* __restrict__ gA,
                                             const unsigned char* __restrict__ g8,
                                             const int* __restrict__ cnt2d,
                                             const int* __restrict__ lofs2d,
                                             unsigned int* __restrict__ edata,
                                             uint2* __restrict__ nfo,
                                             const void* __restrict__ X,
                                             const unsigned short* __restrict__ Wt,
                                             unsigned short* __restrict__ Hh,
                                             const int* __restrict__ flags,
                                             int N, int B, int chunk) {
    __shared__ unsigned char lds[49152];
    int t = threadIdx.x, g = blockIdx.x;

    if (g < B) {
        unsigned int* raw = (unsigned int*)lds;
        unsigned char* r8 = lds + 24576;
        int* h   = (int*)(lds + 30720);
        int* tmp = (int*)(lds + 31744);
        int* s_cnt = (int*)(lds + 32768);
        int b = g;
        int segc = cnt2d[b * G1 + t];
        int sbase = t * chunk + lofs2d[b * G1 + t];
        int v = segc;
        tmp[t] = v;
        __syncthreads();
        for (int d = 1; d < 256; d <<= 1) {
            int x = (t >= d) ? tmp[t - d] : 0;
            __syncthreads();
            tmp[t] += x;
            __syncthreads();
        }
        int lo = tmp[t] - v;
        if (t == 255) s_cnt[0] = tmp[255];
        int j = 0;
        for (; j + 3 < segc; j += 4) {
            unsigned int a0 = gA[sbase + j], a1 = gA[sbase + j + 1];
            unsigned int a2 = gA[sbase + j + 2], a3 = gA[sbase + j + 3];
            unsigned char c0 = g8[sbase + j], c1 = g8[sbase + j + 1];
            unsigned char c2 = g8[sbase + j + 2], c3 = g8[sbase + j + 3];
            int i0 = lo + j;
            if (i0 + 3 < P3CAP) {
                raw[i0] = a0; raw[i0 + 1] = a1; raw[i0 + 2] = a2; raw[i0 + 3] = a3;
                r8[i0] = c0; r8[i0 + 1] = c1; r8[i0 + 2] = c2; r8[i0 + 3] = c3;
            }
        }
        for (; j < segc; ++j) {
            int idx = lo + j;
            if (idx < P3CAP) { raw[idx] = gA[sbase + j]; r8[idx] = g8[sbase + j]; }
        }
        h[t] = 0;
        __syncthreads();
        int cnt = s_cnt[0]; if (cnt > P3CAP) cnt = P3CAP;
        for (int i = t; i < cnt; i += 256) atomicAdd(&h[r8[i]], 1);
        __syncthreads();
        int deg = h[t];
        int pd = (deg + 7) & ~7;
        tmp[t] = pd;
        __syncthreads();
        for (int d = 1; d < 256; d <<= 1) {
            int x = (t >= d) ? tmp[t - d] : 0;
            __syncthreads();
            tmp[t] += x;
            __syncthreads();
        }
        int pexcl = tmp[t] - pd;
        int node0 = b << 8;
        int gbase = b * CAPB;
        if (node0 + t < N) nfo[node0 + t] = make_uint2((unsigned)(gbase + pexcl), (unsigned)deg);
        h[t] = pexcl;
        // zero only this node's pad-gap slots (disjoint from scatter targets)
        for (int zz = deg; zz < pd; ++zz) edata[gbase + pexcl + zz] = 0;
        __syncthreads();
        for (int i = t; i < cnt; i += 256) {
            int pos = atomicAdd(&h[r8[i]], 1);
            if (pos < CAPB) edata[gbase + pos] = raw[i];
        }
        return;
    }

    // ================= layer-1 GEMM role =================
    unsigned char* xs = lds;
    unsigned char* wt = lds + 16384;
    int node0 = (g - B) * 64;
    int f32in = flags[0];

#pragma unroll
    for (int it = 0; it < 8; ++it) {
        int c = t + it * 256;
        int row = c >> 4, cc = c & 15;
        uint4 v = *(const uint4*)(Wt + row * 128 + cc * 8);
        int off = (row * 256 + cc * 16) ^ ((row & 7) << 4);
        *(uint4*)(wt + off) = v;
    }
#pragma unroll
    for (int it = 0; it < 4; ++it) {
        int c = t + it * 256;
        int row = c >> 4, cc = c & 15;
        int gg = node0 + row;
        uint4 v = make_uint4(0, 0, 0, 0);
        if (gg < N) {
            if (f32in) {
                const float* xr = (const float*)X + (size_t)gg * 128 + cc * 8;
                float4 f0 = *(const float4*)xr;
                float4 f1 = *(const float4*)(xr + 4);
                v.x = pk2(f0.x, f0.y); v.y = pk2(f0.z, f0.w);
                v.z = pk2(f1.x, f1.y); v.w = pk2(f1.z, f1.w);
            } else {
                v = *(const uint4*)((const unsigned short*)X + (size_t)gg * 128 + cc * 8);
            }
        }
        int off = (row * 256 + cc * 16) ^ ((row & 7) << 4);
        *(uint4*)(xs + off) = v;
    }
    __syncthreads();

    int w = t >> 6, l = t & 63;
    int arow = l & 15;
    int apart = l >> 4;
    f32x4 acc[8];
#pragma unroll
    for (int ct = 0; ct < 8; ++ct) acc[ct] = (f32x4){0.f, 0.f, 0.f, 0.f};

#pragma unroll
    for (int ks = 0; ks < 4; ++ks) {
        int grow = w * 16 + arow;
        int aoff = (grow * 256 + ks * 64 + apart * 16) ^ ((grow & 7) << 4);
        s16x8 afrag = *(const s16x8*)(xs + aoff);
#pragma unroll
        for (int ct = 0; ct < 8; ++ct) {
            int brow = ct * 16 + arow;
            int boff = (brow * 256 + ks * 64 + apart * 16) ^ ((brow & 7) << 4);
            s16x8 bfrag = *(const s16x8*)(wt + boff);
            acc[ct] = __builtin_amdgcn_mfma_f32_16x16x32_bf16(afrag, bfrag, acc[ct], 0, 0, 0);
        }
    }
    int orow0 = node0 + w * 16 + apart * 4;
    int ocol = arow;
#pragma unroll
    for (int ct = 0; ct < 8; ++ct) {
#pragma unroll
        for (int r = 0; r < 4; ++r) {
            int gg = orow0 + r;
            if (gg < N) {
                __half hh = __float2half(acc[ct][r]);
                Hh[(size_t)gg * 128 + ct * 16 + ocol] = __half_as_ushort(hh);
            }
        }
    }
}

// fused: agg layer-1 + LN + ReLU + (x W2) MFMA -> Hh2 (f16).
// 16 nodes/block (16 lanes each, 8 feats/lane); post-LN rows staged in LDS.
__global__ __launch_bounds__(256) void k_agg_gemm(const unsigned short* __restrict__ Hh,
                                                  const unsigned int* __restrict__ edata,
                                                  const uint2* __restrict__ nfo,
                                                  const float* __restrict__ bias,
                                                  const float* __restrict__ g,
                                                  const float* __restrict__ be,
                                                  const unsigned short* __restrict__ W2t,
                                                  unsigned short* __restrict__ Hh2,
                                                  int N) {
    __shared__ unsigned char lds[36864];   // wt 32KB + xs 4KB
    unsigned char* wt = lds;
    unsigned char* xs = lds + 32768;
    int t = threadIdx.x;
    int node0 = blockIdx.x * 16;
#pragma unroll
    for (int it = 0; it < 8; ++it) {
        int c = t + it * 256;
        int row = c >> 4, cc = c & 15;
        uint4 v = *(const uint4*)(W2t + row * 128 + cc * 8);
        int off = (row * 256 + cc * 16) ^ ((row & 7) << 4);
        *(uint4*)(wt + off) = v;
    }
    int l16 = t & 15;
    int nodeLocal = t >> 4;
    int node = node0 + nodeLocal;
    uint4 xv = make_uint4(0, 0, 0, 0);
    if (node < N) {
        uint2 info = nfo[node];
        int base = (int)info.x, deg = (int)info.y;
        __half2 a01 = u2h2(0u), a23 = u2h2(0u), a45 = u2h2(0u), a67 = u2h2(0u);
        const uint4* Hl = (const uint4*)Hh + l16;
        for (int b0 = 0; b0 < deg; b0 += 8) {
            const uint4* ep = (const uint4*)(edata + base + b0);
            uint4 q0 = ep[0], q1 = ep[1];
            uint4 h0 = Hl[(size_t)(q0.x & 0xffffu) << 4];
            uint4 h1 = Hl[(size_t)(q0.y & 0xffffu) << 4];
            uint4 h2 = Hl[(size_t)(q0.z & 0xffffu) << 4];
            uint4 h3 = Hl[(size_t)(q0.w & 0xffffu) << 4];
            uint4 h4 = Hl[(size_t)(q1.x & 0xffffu) << 4];
            uint4 h5 = Hl[(size_t)(q1.y & 0xffffu) << 4];
            uint4 h6 = Hl[(size_t)(q1.z & 0xffffu) << 4];
            uint4 h7 = Hl[(size_t)(q1.w & 0xffffu) << 4];
            unsigned int wb; __half2 w2;
#define ACC8(hh, wsrc)                                                        \
            wb = (wsrc) >> 16; w2 = u2h2(wb | (wb << 16));                    \
            a01 = __hfma2(u2h2(hh.x), w2, a01); a23 = __hfma2(u2h2(hh.y), w2, a23); \
            a45 = __hfma2(u2h2(hh.z), w2, a45); a67 = __hfma2(u2h2(hh.w), w2, a67);
            ACC8(h0, q0.x) ACC8(h1, q0.y) ACC8(h2, q0.z) ACC8(h3, q0.w)
            ACC8(h4, q1.x) ACC8(h5, q1.y) ACC8(h6, q1.z) ACC8(h7, q1.w)
#undef ACC8
        }
        float4 bv0 = ((const float4*)bias)[2 * l16];
        float4 bv1 = ((const float4*)bias)[2 * l16 + 1];
        float a0 = __low2float(a01) + bv0.x, a1 = __high2float(a01) + bv0.y;
        float a2 = __low2float(a23) + bv0.z, a3 = __high2float(a23) + bv0.w;
        float a4 = __low2float(a45) + bv1.x, a5 = __high2float(a45) + bv1.y;
        float a6 = __low2float(a67) + bv1.z, a7 = __high2float(a67) + bv1.w;
        float s = ((a0 + a1) + (a2 + a3)) + ((a4 + a5) + (a6 + a7));
#pragma unroll
        for (int m = 8; m >= 1; m >>= 1) s += __shfl_xor(s, m, 64);
        float mu = s * (1.f / 128.f);
        float d0 = a0 - mu, d1 = a1 - mu, d2 = a2 - mu, d3 = a3 - mu;
        float d4 = a4 - mu, d5 = a5 - mu, d6 = a6 - mu, d7 = a7 - mu;
        float q = ((d0 * d0 + d1 * d1) + (d2 * d2 + d3 * d3)) +
                  ((d4 * d4 + d5 * d5) + (d6 * d6 + d7 * d7));
#pragma unroll
        for (int m = 8; m >= 1; m >>= 1) q += __shfl_xor(q, m, 64);
        float rs = rsqrtf(q * (1.f / 128.f) + LN_EPS);
        float4 gv0 = ((const float4*)g)[2 * l16], gv1 = ((const float4*)g)[2 * l16 + 1];
        float4 bev0 = ((const float4*)be)[2 * l16], bev1 = ((const float4*)be)[2 * l16 + 1];
        float r0 = fmaxf(d0 * rs * gv0.x + bev0.x, 0.f);
        float r1 = fmaxf(d1 * rs * gv0.y + bev0.y, 0.f);
        float r2 = fmaxf(d2 * rs * gv0.z + bev0.z, 0.f);
        float r3 = fmaxf(d3 * rs * gv0.w + bev0.w, 0.f);
        float r4 = fmaxf(d4 * rs * gv1.x + bev1.x, 0.f);
        float r5 = fmaxf(d5 * rs * gv1.y + bev1.y, 0.f);
        float r6 = fmaxf(d6 * rs * gv1.z + bev1.z, 0.f);
        float r7 = fmaxf(d7 * rs * gv1.w + bev1.w, 0.f);
        xv.x = pk2(r0, r1); xv.y = pk2(r2, r3);
        xv.z = pk2(r4, r5); xv.w = pk2(r6, r7);
    }
    {
        int off = (nodeLocal * 256 + l16 * 16) ^ ((nodeLocal & 7) << 4);
        *(uint4*)(xs + off) = xv;
    }
    __syncthreads();
    int w = t >> 6, l = t & 63;
    int arow = l & 15;
    int apart = l >> 4;
    f32x4 acc0 = (f32x4){0.f, 0.f, 0.f, 0.f};
    f32x4 acc1 = (f32x4){0.f, 0.f, 0.f, 0.f};
#pragma unroll
    for (int ks = 0; ks < 4; ++ks) {
        int aoff = (arow * 256 + ks * 64 + apart * 16) ^ ((arow & 7) << 4);
        s16x8 afrag = *(const s16x8*)(xs + aoff);
        int brow0 = (w * 2 + 0) * 16 + arow;
        int brow1 = (w * 2 + 1) * 16 + arow;
        s16x8 bf0 = *(const s16x8*)(wt + ((brow0 * 256 + ks * 64 + apart * 16) ^ ((brow0 & 7) << 4)));
        s16x8 bf1 = *(const s16x8*)(wt + ((brow1 * 256 + ks * 64 + apart * 16) ^ ((brow1 & 7) << 4)));
        acc0 = __builtin_amdgcn_mfma_f32_16x16x32_bf16(afrag, bf0, acc0, 0, 0, 0);
        acc1 = __builtin_amdgcn_mfma_f32_16x16x32_bf16(afrag, bf1, acc1, 0, 0, 0);
    }
    int orow0 = node0 + apart * 4;
#pragma unroll
    for (int r = 0; r < 4; ++r) {
        int gg = orow0 + r;
        if (gg < N) {
            __half h0 = __float2half(acc0[r]);
            __half h1 = __float2half(acc1[r]);
            Hh2[(size_t)gg * 128 + (w * 2 + 0) * 16 + arow] = __half_as_ushort(h0);
            Hh2[(size_t)gg * 128 + (w * 2 + 1) * 16 + arow] = __half_as_ushort(h1);
        }
    }
}

// final: out = relu(LN(bias + sum_e ew*H[src])); 4 nodes per wave (16 lanes each).
__global__ __launch_bounds__(256) void k_agg_ln(const unsigned short* __restrict__ Hh,
                                                const unsigned int* __restrict__ edata,
                                                const uint2* __restrict__ nfo,
                                                const float* __restrict__ bias,
                                                const float* __restrict__ g,
                                                const float* __restrict__ be,
                                                void* __restrict__ outAny,
                                                const int* __restrict__ flags, int N) {
    int t = threadIdx.x;
    int l16 = t & 15;
    int node = blockIdx.x * 16 + (t >> 4);
    if (node >= N) return;
    uint2 info = nfo[node];
    int base = (int)info.x, deg = (int)info.y;
    __half2 a01 = u2h2(0u), a23 = u2h2(0u), a45 = u2h2(0u), a67 = u2h2(0u);
    const uint4* Hl = (const uint4*)Hh + l16;
    for (int b0 = 0; b0 < deg; b0 += 8) {
        const uint4* ep = (const uint4*)(edata + base + b0);
        uint4 q0 = ep[0], q1 = ep[1];
        uint4 h0 = Hl[(size_t)(q0.x & 0xffffu) << 4];
        uint4 h1 = Hl[(size_t)(q0.y & 0xffffu) << 4];
        uint4 h2 = Hl[(size_t)(q0.z & 0xffffu) << 4];
        uint4 h3 = Hl[(size_t)(q0.w & 0xffffu) << 4];
        uint4 h4 = Hl[(size_t)(q1.x & 0xffffu) << 4];
        uint4 h5 = Hl[(size_t)(q1.y & 0xffffu) << 4];
        uint4 h6 = Hl[(size_t)(q1.z & 0xffffu) << 4];
        uint4 h7 = Hl[(size_t)(q1.w & 0xffffu) << 4];
        unsigned int wb; __half2 w2;
#define ACC8(hh, wsrc)                                                        \
        wb = (wsrc) >> 16; w2 = u2h2(wb | (wb << 16));                        \
        a01 = __hfma2(u2h2(hh.x), w2, a01); a23 = __hfma2(u2h2(hh.y), w2, a23); \
        a45 = __hfma2(u2h2(hh.z), w2, a45); a67 = __hfma2(u2h2(hh.w), w2, a67);
        ACC8(h0, q0.x) ACC8(h1, q0.y) ACC8(h2, q0.z) ACC8(h3, q0.w)
        ACC8(h4, q1.x) ACC8(h5, q1.y) ACC8(h6, q1.z) ACC8(h7, q1.w)
#undef ACC8
    }
    float4 bv0 = ((const float4*)bias)[2 * l16];
    float4 bv1 = ((const float4*)bias)[2 * l16 + 1];
    float a0 = __low2float(a01) + bv0.x, a1 = __high2float(a01) + bv0.y;
    float a2 = __low2float(a23) + bv0.z, a3 = __high2float(a23) + bv0.w;
    float a4 = __low2float(a45) + bv1.x, a5 = __high2float(a45) + bv1.y;
    float a6 = __low2float(a67) + bv1.z, a7 = __high2float(a67) + bv1.w;
    float s = ((a0 + a1) + (a2 + a3)) + ((a4 + a5) + (a6 + a7));
#pragma unroll
    for (int m = 8; m >= 1; m >>= 1) s += __shfl_xor(s, m, 64);
    float mu = s * (1.f / 128.f);
    float d0 = a0 - mu, d1 = a1 - mu, d2 = a2 - mu, d3 = a3 - mu;
    float d4 = a4 - mu, d5 = a5 - mu, d6 = a6 - mu, d7 = a7 - mu;
    float q = ((d0 * d0 + d1 * d1) + (d2 * d2 + d3 * d3)) +
              ((d4 * d4 + d5 * d5) + (d6 * d6 + d7 * d7));
#pragma unroll
    for (int m = 8; m >= 1; m >>= 1) q += __shfl_xor(q, m, 64);
    float rs = rsqrtf(q * (1.f / 128.f) + LN_EPS);
    float4 gv0 = ((const float4*)g)[2 * l16], gv1 = ((const float4*)g)[2 * l16 + 1];
    float4 bev0 = ((const float4*)be)[2 * l16], bev1 = ((const float4*)be)[2 * l16 + 1];
    float r0 = fmaxf(d0 * rs * gv0.x + bev0.x, 0.f);
    float r1 = fmaxf(d1 * rs * gv0.y + bev0.y, 0.f);
    float r2 = fmaxf(d2 * rs * gv0.z + bev0.z, 0.f);
    float r3 = fmaxf(d3 * rs * gv0.w + bev0.w, 0.f);
    float r4 = fmaxf(d4 * rs * gv1.x + bev1.x, 0.f);
    float r5 = fmaxf(d5 * rs * gv1.y + bev1.y, 0.f);
    float r6 = fmaxf(d6 * rs * gv1.z + bev1.z, 0.f);
    float r7 = fmaxf(d7 * rs * gv1.w + bev1.w, 0.f);
    if (flags[0]) {
        float4* o = (float4*)outAny + (size_t)node * 32 + 2 * l16;
        o[0] = make_float4(r0, r1, r2, r3);
        o[1] = make_float4(r4, r5, r6, r7);
    } else {
        uint4 o;
        o.x = pk2(r0, r1); o.y = pk2(r2, r3);
        o.z = pk2(r4, r5); o.w = pk2(r6, r7);
        ((uint4*)outAny)[(size_t)node * 16 + l16] = o;
    }
}

extern "C" void kernel_launch(void* const* d_in, const int* in_sizes, int n_in,
                              void* d_out, int out_size, void* d_ws, size_t ws_size,
                              hipStream_t stream) {
    const unsigned short* x_u16 = (const unsigned short*)d_in[0];
    const int*            ei    = (const int*)d_in[1];

    const int N = in_sizes[0] / 128;
    const int E = in_sizes[2];
    const int B = (N + 255) >> 8;          // buckets of 256 nodes (<=256)
    const int chunk = (E + G1 - 1) / G1;

    // ---- workspace layout ----
    unsigned short* Hh2 = (unsigned short*)d_ws;           // N*128 f16
    unsigned short* Hh  = Hh2 + (size_t)N * 128;           // N*128 f16
    unsigned int* gA    = (unsigned int*)(Hh + (size_t)N * 128); // E
    unsigned int* edata = gA + E;                          // B*CAPB
    unsigned char* g8   = (unsigned char*)(edata + (size_t)B * CAPB); // E (pad 4)
    int* cnt2d  = (int*)(g8 + ((E + 3) & ~3));             // 256*256
    int* lofs2d = cnt2d + 65536;                           // 256*256
    uint2* nfo  = (uint2*)(lofs2d + 65536);                // N
    int* flags  = (int*)(nfo + N);                         // 8
    unsigned short* Wt1 = (unsigned short*)(flags + 8);    // 16384 bf16
    unsigned short* Wt2 = Wt1 + 16384;                     // 16384 bf16
    float* sm   = (float*)(Wt2 + 16384);                   // 6*128 f32
    float* b1f  = sm;
    float* b2f_ = sm + 128;
    float* g1f  = sm + 256;
    float* g2f  = sm + 384;
    float* be1f = sm + 512;
    float* be2f = sm + 640;

    const int nodeBlocks = (N + 15) / 16;
    const int gemmBlocks = (N + 63) / 64;

    // ---- pass1: edge binning + weight prep (merged, 320 blocks) ----
    k_p1<<<G1 + 64, 256, 0, stream>>>(x_u16, ei, d_in[2],
                                      d_in[3], d_in[5], d_in[4], d_in[6],
                                      d_in[7], d_in[9], d_in[8], d_in[10],
                                      Wt1, Wt2, sm,
                                      E, B, chunk, gA, g8, cnt2d, lofs2d, flags);

    // ---- pass3 CSR finalize + layer-1 GEMM (merged, independent roles) ----
    k_p3g<<<B + gemmBlocks, 256, 0, stream>>>(gA, g8, cnt2d, lofs2d, edata, nfo,
                                              d_in[0], Wt1, Hh, flags, N, B, chunk);

    // ---- layer-1 aggregate + LN + ReLU + layer-2 GEMM (fused) ----
    k_agg_gemm<<<nodeBlocks, 256, 0, stream>>>(Hh, edata, nfo, b1f, g1f, be1f,
                                               Wt2, Hh2, N);

    // ---- layer-2 aggregate + LN + ReLU -> d_out ----
    k_agg_ln<<<nodeBlocks, 256, 0, stream>>>(Hh2, edata, nfo, b2f_, g2f, be2f,
                                             d_out, flags, N);
}

// Round 16
// 97.795 us; speedup vs baseline: 3.3266x; 1.0266x over previous
//
#include <hip/hip_runtime.h>
#include <hip/hip_fp16.h>
#include <stdint.h>

#define LN_EPS 1e-5f
#define G1 256
#define P3CAP 6144
#define CAPB 6144

typedef __attribute__((ext_vector_type(8))) short s16x8;
typedef __attribute__((ext_vector_type(4))) float f32x4;

__device__ __forceinline__ float b2f(unsigned short u) {
    union { unsigned int i; float f; } v; v.i = ((unsigned int)u) << 16; return v.f;
}
__device__ __forceinline__ unsigned short f2b(float f) {
    union { float f; unsigned int i; } v; v.f = f;
    unsigned int u = v.i;
    return (unsigned short)((u + 0x7fffu + ((u >> 16) & 1u)) >> 16);
}
__device__ __forceinline__ unsigned int pk2(float a, float b) {
    return (unsigned int)f2b(a) | ((unsigned int)f2b(b) << 16);
}
__device__ __forceinline__ __half2 u2h2(unsigned int u) {
    union { unsigned int i; __half2 h; } v; v.i = u; return v.h;
}
__device__ __forceinline__ float rdf(const void* p, int i, int f32flag) {
    return f32flag ? ((const float*)p)[i] : b2f(((const unsigned short*)p)[i]);
}

// pass 1 (320 blocks): blocks [0,256) bin edges by bucket (dst>>8);
// blocks [256,320) transpose W1/W2 -> bf16 and convert small params.
__global__ __launch_bounds__(256) void k_p1(const unsigned short* __restrict__ xu,
                                            const int* __restrict__ ei, const void* __restrict__ ew,
                                            const void* W1, const void* W2,
                                            const void* b1, const void* b2_,
                                            const void* g1, const void* g2,
                                            const void* be1, const void* be2,
                                            unsigned short* __restrict__ Wt1,
                                            unsigned short* __restrict__ Wt2,
                                            float* __restrict__ sm,
                                            int E, int B, int chunk,
                                            unsigned int* __restrict__ gA,
                                            unsigned char* __restrict__ g8,
                                            int* __restrict__ cnt2d, int* __restrict__ lofs2d,
                                            int* __restrict__ flags) {
    __shared__ int hist[256], cur[256], tmp[256];
    __shared__ unsigned int bin32[4096];
    __shared__ unsigned char bin8[4096];
    int t = threadIdx.x, g = blockIdx.x;
    // ---- local dtype detection ----
    if (t < 2) hist[t] = 0;
    __syncthreads();
    int c1 = 0;
    for (int i = t; i < 2048; i += 256)
        if (fabsf(b2f(xu[i])) > 1e6f) ++c1;
    if (c1) atomicAdd(&hist[0], c1);
    int mn = (E < 1024) ? E : 1024;
    int z = 0;
    for (int i = t; i < mn; i += 256)
        if (ei[2 * i + 1] == 0) ++z;
    if (z) atomicAdd(&hist[1], z);
    __syncthreads();
    int f32f = (hist[0] > 32) ? 1 : 0;
    int f64  = (hist[1] > (mn >> 1)) ? 1 : 0;
    if (g == 0 && t == 0) { flags[0] = f32f; flags[1] = f64; }

    if (g >= G1) {
        int i = (g - G1) * 256 + t;      // 64*256 = 16384
        int k = i >> 7, j = i & 127;
        Wt1[j * 128 + k] = f2b(rdf(W1, i, f32f));
        Wt2[j * 128 + k] = f2b(rdf(W2, i, f32f));
        if (g == G1 && t < 128) {
            sm[t]       = rdf(b1, t, f32f);
            sm[128 + t] = rdf(b2_, t, f32f);
            sm[256 + t] = rdf(g1, t, f32f);
            sm[384 + t] = rdf(g2, t, f32f);
            sm[512 + t] = rdf(be1, t, f32f);
            sm[640 + t] = rdf(be2, t, f32f);
        }
        return;
    }
    __syncthreads();
    // ---- binning ----
    int base = g * chunk;
    int cnt = E - base; if (cnt > chunk) cnt = chunk; if (cnt < 0) cnt = 0;
    hist[t] = 0;
    __syncthreads();
    for (int i = t; i < cnt; i += 256) {
        int e = base + i;
        int d = f64 ? ei[2 * E + 2 * e] : ei[E + e];
        atomicAdd(&hist[d >> 8], 1);
    }
    __syncthreads();
    int v = hist[t];
    tmp[t] = v;
    __syncthreads();
    for (int d = 1; d < 256; d <<= 1) {
        int x = (t >= d) ? tmp[t - d] : 0;
        __syncthreads();
        tmp[t] += x;
        __syncthreads();
    }
    int excl = tmp[t] - v;
    cur[t] = excl;
    if (t < B) { cnt2d[t * G1 + g] = v; lofs2d[t * G1 + g] = excl; }
    __syncthreads();
    for (int i = t; i < cnt; i += 256) {
        int e = base + i;
        int d, sN;
        if (f64) { d = ei[2 * E + 2 * e]; sN = ei[2 * e]; }
        else     { d = ei[E + e];         sN = ei[e]; }
        float w = f32f ? ((const float*)ew)[e] : b2f(((const unsigned short*)ew)[e]);
        __half wh = __float2half(w);
        int p = atomicAdd(&cur[d >> 8], 1);
        bin32[p] = (unsigned int)(sN & 0xffff) | ((unsigned int)__half_as_ushort(wh) << 16);
        bin8[p]  = (unsigned char)(d & 255);
    }
    __syncthreads();
    for (int j = t; j < cnt; j += 256) {
        gA[base + j] = bin32[j];
        g8[base + j] = bin8[j];
    }
}

// dual-role kernel: blocks [0,B) = pass-3 CSR finalize (direct global scatter);
// blocks [B, B+gemmBlocks) = layer-1 MFMA GEMM.
__global__ __launch_bounds__(256) void k_p3g(const unsigned int* __restrict__ gA,
                                             const unsigned char* __restrict__ g8,
                                             const int* __restrict__ cnt2d,
                                             const int* __restrict__ lofs2d,
                                             unsigned int* __restrict__ edata,
                                             uint2* __restrict__ nfo,
                                             const void* __restrict__ X,
                                             const unsigned short* __restrict__ Wt,
                                             unsigned short* __restrict__ Hh,
                                             const int* __restrict__ flags,
                                             int N, int B, int chunk) {
    __shared__ unsigned char lds[49152];
    int t = threadIdx.x, g = blockIdx.x;

    if (g < B) {
        unsigned int* raw = (unsigned int*)lds;
        unsigned char* r8 = lds + 24576;
        int* h   = (int*)(lds + 30720);
        int* tmp = (int*)(lds + 31744);
        int* s_cnt = (int*)(lds + 32768);
        int b = g;
        int segc = cnt2d[b * G1 + t];
        int sbase = t * chunk + lofs2d[b * G1 + t];
        int v = segc;
        tmp[t] = v;
        __syncthreads();
        for (int d = 1; d < 256; d <<= 1) {
            int x = (t >= d) ? tmp[t - d] : 0;
            __syncthreads();
            tmp[t] += x;
            __syncthreads();
        }
        int lo = tmp[t] - v;
        if (t == 255) s_cnt[0] = tmp[255];
        int j = 0;
        for (; j + 3 < segc; j += 4) {
            unsigned int a0 = gA[sbase + j], a1 = gA[sbase + j + 1];
            unsigned int a2 = gA[sbase + j + 2], a3 = gA[sbase + j + 3];
            unsigned char c0 = g8[sbase + j], c1 = g8[sbase + j + 1];
            unsigned char c2 = g8[sbase + j + 2], c3 = g8[sbase + j + 3];
            int i0 = lo + j;
            if (i0 + 3 < P3CAP) {
                raw[i0] = a0; raw[i0 + 1] = a1; raw[i0 + 2] = a2; raw[i0 + 3] = a3;
                r8[i0] = c0; r8[i0 + 1] = c1; r8[i0 + 2] = c2; r8[i0 + 3] = c3;
            }
        }
        for (; j < segc; ++j) {
            int idx = lo + j;
            if (idx < P3CAP) { raw[idx] = gA[sbase + j]; r8[idx] = g8[sbase + j]; }
        }
        h[t] = 0;
        __syncthreads();
        int cnt = s_cnt[0]; if (cnt > P3CAP) cnt = P3CAP;
        for (int i = t; i < cnt; i += 256) atomicAdd(&h[r8[i]], 1);
        __syncthreads();
        int deg = h[t];
        int pd = (deg + 7) & ~7;
        tmp[t] = pd;
        __syncthreads();
        for (int d = 1; d < 256; d <<= 1) {
            int x = (t >= d) ? tmp[t - d] : 0;
            __syncthreads();
            tmp[t] += x;
            __syncthreads();
        }
        int pexcl = tmp[t] - pd;
        int node0 = b << 8;
        int gbase = b * CAPB;
        if (node0 + t < N) nfo[node0 + t] = make_uint2((unsigned)(gbase + pexcl), (unsigned)deg);
        h[t] = pexcl;
        // zero only this node's pad-gap slots (disjoint from scatter targets)
        for (int zz = deg; zz < pd; ++zz) edata[gbase + pexcl + zz] = 0;
        __syncthreads();
        for (int i = t; i < cnt; i += 256) {
            int pos = atomicAdd(&h[r8[i]], 1);
            if (pos < CAPB) edata[gbase + pos] = raw[i];
        }
        return;
    }

    // ================= layer-1 GEMM role =================
    unsigned char* xs = lds;
    unsigned char* wt = lds + 16384;
    int node0 = (g - B) * 64;
    int f32in = flags[0];

#pragma unroll
    for (int it = 0; it < 8; ++it) {
        int c = t + it * 256;
        int row = c >> 4, cc = c & 15;
        uint4 v = *(const uint4*)(Wt + row * 128 + cc * 8);
        int off = (row * 256 + cc * 16) ^ ((row & 7) << 4);
        *(uint4*)(wt + off) = v;
    }
#pragma unroll
    for (int it = 0; it < 4; ++it) {
        int c = t + it * 256;
        int row = c >> 4, cc = c & 15;
        int gg = node0 + row;
        uint4 v = make_uint4(0, 0, 0, 0);
        if (gg < N) {
            if (f32in) {
                const float* xr = (const float*)X + (size_t)gg * 128 + cc * 8;
                float4 f0 = *(const float4*)xr;
                float4 f1 = *(const float4*)(xr + 4);
                v.x = pk2(f0.x, f0.y); v.y = pk2(f0.z, f0.w);
                v.z = pk2(f1.x, f1.y); v.w = pk2(f1.z, f1.w);
            } else {
                v = *(const uint4*)((const unsigned short*)X + (size_t)gg * 128 + cc * 8);
            }
        }
        int off = (row * 256 + cc * 16) ^ ((row & 7) << 4);
        *(uint4*)(xs + off) = v;
    }
    __syncthreads();

    int w = t >> 6, l = t & 63;
    int arow = l & 15;
    int apart = l >> 4;
    f32x4 acc[8];
#pragma unroll
    for (int ct = 0; ct < 8; ++ct) acc[ct] = (f32x4){0.f, 0.f, 0.f, 0.f};

#pragma unroll
    for (int ks = 0; ks < 4; ++ks) {
        int grow = w * 16 + arow;
        int aoff = (grow * 256 + ks * 64 + apart * 16) ^ ((grow & 7) << 4);
        s16x8 afrag = *(const s16x8*)(xs + aoff);
#pragma unroll
        for (int ct = 0; ct < 8; ++ct) {
            int brow = ct * 16 + arow;
            int boff = (brow * 256 + ks * 64 + apart * 16) ^ ((brow & 7) << 4);
            s16x8 bfrag = *(const s16x8*)(wt + boff);
            acc[ct] = __builtin_amdgcn_mfma_f32_16x16x32_bf16(afrag, bfrag, acc[ct], 0, 0, 0);
        }
    }
    int orow0 = node0 + w * 16 + apart * 4;
    int ocol = arow;
#pragma unroll
    for (int ct = 0; ct < 8; ++ct) {
#pragma unroll
        for (int r = 0; r < 4; ++r) {
            int gg = orow0 + r;
            if (gg < N) {
                __half hh = __float2half(acc[ct][r]);
                Hh[(size_t)gg * 128 + ct * 16 + ocol] = __half_as_ushort(hh);
            }
        }
    }
}

// aggregate core with descriptor double-buffering: next batch's edata
// descriptors issue before the current batch's row gathers.
#define AGG_BODY(Hsrc)                                                        \
    uint2 info = nfo[node];                                                   \
    int base = (int)info.x, deg = (int)info.y;                                \
    __half2 a01 = u2h2(0u), a23 = u2h2(0u), a45 = u2h2(0u), a67 = u2h2(0u);   \
    const uint4* Hl = (const uint4*)(Hsrc) + l16;                             \
    const uint4* ep = (const uint4*)(edata + base);                           \
    int nb = (deg + 7) >> 3;                                                  \
    uint4 q0 = make_uint4(0, 0, 0, 0), q1 = q0;                               \
    if (nb > 0) { q0 = ep[0]; q1 = ep[1]; }                                   \
    for (int ib = 0; ib < nb; ++ib) {                                         \
        uint4 n0 = q0, n1 = q1;                                               \
        if (ib + 1 < nb) { n0 = ep[2 * ib + 2]; n1 = ep[2 * ib + 3]; }        \
        uint4 h0 = Hl[(size_t)(q0.x & 0xffffu) << 4];                         \
        uint4 h1 = Hl[(size_t)(q0.y & 0xffffu) << 4];                         \
        uint4 h2 = Hl[(size_t)(q0.z & 0xffffu) << 4];                         \
        uint4 h3 = Hl[(size_t)(q0.w & 0xffffu) << 4];                         \
        uint4 h4 = Hl[(size_t)(q1.x & 0xffffu) << 4];                         \
        uint4 h5 = Hl[(size_t)(q1.y & 0xffffu) << 4];                         \
        uint4 h6 = Hl[(size_t)(q1.z & 0xffffu) << 4];                         \
        uint4 h7 = Hl[(size_t)(q1.w & 0xffffu) << 4];                         \
        unsigned int wb; __half2 w2;                                          \
        wb = q0.x >> 16; w2 = u2h2(wb | (wb << 16));                          \
        a01 = __hfma2(u2h2(h0.x), w2, a01); a23 = __hfma2(u2h2(h0.y), w2, a23); \
        a45 = __hfma2(u2h2(h0.z), w2, a45); a67 = __hfma2(u2h2(h0.w), w2, a67); \
        wb = q0.y >> 16; w2 = u2h2(wb | (wb << 16));                          \
        a01 = __hfma2(u2h2(h1.x), w2, a01); a23 = __hfma2(u2h2(h1.y), w2, a23); \
        a45 = __hfma2(u2h2(h1.z), w2, a45); a67 = __hfma2(u2h2(h1.w), w2, a67); \
        wb = q0.z >> 16; w2 = u2h2(wb | (wb << 16));                          \
        a01 = __hfma2(u2h2(h2.x), w2, a01); a23 = __hfma2(u2h2(h2.y), w2, a23); \
        a45 = __hfma2(u2h2(h2.z), w2, a45); a67 = __hfma2(u2h2(h2.w), w2, a67); \
        wb = q0.w >> 16; w2 = u2h2(wb | (wb << 16));                          \
        a01 = __hfma2(u2h2(h3.x), w2, a01); a23 = __hfma2(u2h2(h3.y), w2, a23); \
        a45 = __hfma2(u2h2(h3.z), w2, a45); a67 = __hfma2(u2h2(h3.w), w2, a67); \
        wb = q1.x >> 16; w2 = u2h2(wb | (wb << 16));                          \
        a01 = __hfma2(u2h2(h4.x), w2, a01); a23 = __hfma2(u2h2(h4.y), w2, a23); \
        a45 = __hfma2(u2h2(h4.z), w2, a45); a67 = __hfma2(u2h2(h4.w), w2, a67); \
        wb = q1.y >> 16; w2 = u2h2(wb | (wb << 16));                          \
        a01 = __hfma2(u2h2(h5.x), w2, a01); a23 = __hfma2(u2h2(h5.y), w2, a23); \
        a45 = __hfma2(u2h2(h5.z), w2, a45); a67 = __hfma2(u2h2(h5.w), w2, a67); \
        wb = q1.z >> 16; w2 = u2h2(wb | (wb << 16));                          \
        a01 = __hfma2(u2h2(h6.x), w2, a01); a23 = __hfma2(u2h2(h6.y), w2, a23); \
        a45 = __hfma2(u2h2(h6.z), w2, a45); a67 = __hfma2(u2h2(h6.w), w2, a67); \
        wb = q1.w >> 16; w2 = u2h2(wb | (wb << 16));                          \
        a01 = __hfma2(u2h2(h7.x), w2, a01); a23 = __hfma2(u2h2(h7.y), w2, a23); \
        a45 = __hfma2(u2h2(h7.z), w2, a45); a67 = __hfma2(u2h2(h7.w), w2, a67); \
        q0 = n0; q1 = n1;                                                     \
    }

// fused: agg layer-1 + LN + ReLU + (x W2) MFMA -> Hh2 (f16).
__global__ __launch_bounds__(256) void k_agg_gemm(const unsigned short* __restrict__ Hh,
                                                  const unsigned int* __restrict__ edata,
                                                  const uint2* __restrict__ nfo,
                                                  const float* __restrict__ bias,
                                                  const float* __restrict__ g,
                                                  const float* __restrict__ be,
                                                  const unsigned short* __restrict__ W2t,
                                                  unsigned short* __restrict__ Hh2,
                                                  int N) {
    __shared__ unsigned char lds[36864];   // wt 32KB + xs 4KB
    unsigned char* wt = lds;
    unsigned char* xs = lds + 32768;
    int t = threadIdx.x;
    int node0 = blockIdx.x * 16;
#pragma unroll
    for (int it = 0; it < 8; ++it) {
        int c = t + it * 256;
        int row = c >> 4, cc = c & 15;
        uint4 v = *(const uint4*)(W2t + row * 128 + cc * 8);
        int off = (row * 256 + cc * 16) ^ ((row & 7) << 4);
        *(uint4*)(wt + off) = v;
    }
    int l16 = t & 15;
    int nodeLocal = t >> 4;
    int node = node0 + nodeLocal;
    uint4 xv = make_uint4(0, 0, 0, 0);
    if (node < N) {
        AGG_BODY(Hh)
        float4 bv0 = ((const float4*)bias)[2 * l16];
        float4 bv1 = ((const float4*)bias)[2 * l16 + 1];
        float a0 = __low2float(a01) + bv0.x, a1 = __high2float(a01) + bv0.y;
        float a2 = __low2float(a23) + bv0.z, a3 = __high2float(a23) + bv0.w;
        float a4 = __low2float(a45) + bv1.x, a5 = __high2float(a45) + bv1.y;
        float a6 = __low2float(a67) + bv1.z, a7 = __high2float(a67) + bv1.w;
        float s = ((a0 + a1) + (a2 + a3)) + ((a4 + a5) + (a6 + a7));
#pragma unroll
        for (int m = 8; m >= 1; m >>= 1) s += __shfl_xor(s, m, 64);
        float mu = s * (1.f / 128.f);
        float d0 = a0 - mu, d1 = a1 - mu, d2 = a2 - mu, d3 = a3 - mu;
        float d4 = a4 - mu, d5 = a5 - mu, d6 = a6 - mu, d7 = a7 - mu;
        float q = ((d0 * d0 + d1 * d1) + (d2 * d2 + d3 * d3)) +
                  ((d4 * d4 + d5 * d5) + (d6 * d6 + d7 * d7));
#pragma unroll
        for (int m = 8; m >= 1; m >>= 1) q += __shfl_xor(q, m, 64);
        float rs = rsqrtf(q * (1.f / 128.f) + LN_EPS);
        float4 gv0 = ((const float4*)g)[2 * l16], gv1 = ((const float4*)g)[2 * l16 + 1];
        float4 bev0 = ((const float4*)be)[2 * l16], bev1 = ((const float4*)be)[2 * l16 + 1];
        float r0 = fmaxf(d0 * rs * gv0.x + bev0.x, 0.f);
        float r1 = fmaxf(d1 * rs * gv0.y + bev0.y, 0.f);
        float r2 = fmaxf(d2 * rs * gv0.z + bev0.z, 0.f);
        float r3 = fmaxf(d3 * rs * gv0.w + bev0.w, 0.f);
        float r4 = fmaxf(d4 * rs * gv1.x + bev1.x, 0.f);
        float r5 = fmaxf(d5 * rs * gv1.y + bev1.y, 0.f);
        float r6 = fmaxf(d6 * rs * gv1.z + bev1.z, 0.f);
        float r7 = fmaxf(d7 * rs * gv1.w + bev1.w, 0.f);
        xv.x = pk2(r0, r1); xv.y = pk2(r2, r3);
        xv.z = pk2(r4, r5); xv.w = pk2(r6, r7);
    }
    {
        int off = (nodeLocal * 256 + l16 * 16) ^ ((nodeLocal & 7) << 4);
        *(uint4*)(xs + off) = xv;
    }
    __syncthreads();
    int w = t >> 6, l = t & 63;
    int arow = l & 15;
    int apart = l >> 4;
    f32x4 acc0 = (f32x4){0.f, 0.f, 0.f, 0.f};
    f32x4 acc1 = (f32x4){0.f, 0.f, 0.f, 0.f};
#pragma unroll
    for (int ks = 0; ks < 4; ++ks) {
        int aoff = (arow * 256 + ks * 64 + apart * 16) ^ ((arow & 7) << 4);
        s16x8 afrag = *(const s16x8*)(xs + aoff);
        int brow0 = (w * 2 + 0) * 16 + arow;
        int brow1 = (w * 2 + 1) * 16 + arow;
        s16x8 bf0 = *(const s16x8*)(wt + ((brow0 * 256 + ks * 64 + apart * 16) ^ ((brow0 & 7) << 4)));
        s16x8 bf1 = *(const s16x8*)(wt + ((brow1 * 256 + ks * 64 + apart * 16) ^ ((brow1 & 7) << 4)));
        acc0 = __builtin_amdgcn_mfma_f32_16x16x32_bf16(afrag, bf0, acc0, 0, 0, 0);
        acc1 = __builtin_amdgcn_mfma_f32_16x16x32_bf16(afrag, bf1, acc1, 0, 0, 0);
    }
    int orow0 = node0 + apart * 4;
#pragma unroll
    for (int r = 0; r < 4; ++r) {
        int gg = orow0 + r;
        if (gg < N) {
            __half h0 = __float2half(acc0[r]);
            __half h1 = __float2half(acc1[r]);
            Hh2[(size_t)gg * 128 + (w * 2 + 0) * 16 + arow] = __half_as_ushort(h0);
            Hh2[(size_t)gg * 128 + (w * 2 + 1) * 16 + arow] = __half_as_ushort(h1);
        }
    }
}

// final: out = relu(LN(bias + sum_e ew*H[src])); 4 nodes per wave (16 lanes each).
__global__ __launch_bounds__(256) void k_agg_ln(const unsigned short* __restrict__ Hh,
                                                const unsigned int* __restrict__ edata,
                                                const uint2* __restrict__ nfo,
                                                const float* __restrict__ bias,
                                                const float* __restrict__ g,
                                                const float* __restrict__ be,
                                                void* __restrict__ outAny,
                                                const int* __restrict__ flags, int N) {
    int t = threadIdx.x;
    int l16 = t & 15;
    int node = blockIdx.x * 16 + (t >> 4);
    if (node >= N) return;
    AGG_BODY(Hh)
    float4 bv0 = ((const float4*)bias)[2 * l16];
    float4 bv1 = ((const float4*)bias)[2 * l16 + 1];
    float a0 = __low2float(a01) + bv0.x, a1 = __high2float(a01) + bv0.y;
    float a2 = __low2float(a23) + bv0.z, a3 = __high2float(a23) + bv0.w;
    float a4 = __low2float(a45) + bv1.x, a5 = __high2float(a45) + bv1.y;
    float a6 = __low2float(a67) + bv1.z, a7 = __high2float(a67) + bv1.w;
    float s = ((a0 + a1) + (a2 + a3)) + ((a4 + a5) + (a6 + a7));
#pragma unroll
    for (int m = 8; m >= 1; m >>= 1) s += __shfl_xor(s, m, 64);
    float mu = s * (1.f / 128.f);
    float d0 = a0 - mu, d1 = a1 - mu, d2 = a2 - mu, d3 = a3 - mu;
    float d4 = a4 - mu, d5 = a5 - mu, d6 = a6 - mu, d7 = a7 - mu;
    float q = ((d0 * d0 + d1 * d1) + (d2 * d2 + d3 * d3)) +
              ((d4 * d4 + d5 * d5) + (d6 * d6 + d7 * d7));
#pragma unroll
    for (int m = 8; m >= 1; m >>= 1) q += __shfl_xor(q, m, 64);
    float rs = rsqrtf(q * (1.f / 128.f) + LN_EPS);
    float4 gv0 = ((const float4*)g)[2 * l16], gv1 = ((const float4*)g)[2 * l16 + 1];
    float4 bev0 = ((const float4*)be)[2 * l16], bev1 = ((const float4*)be)[2 * l16 + 1];
    float r0 = fmaxf(d0 * rs * gv0.x + bev0.x, 0.f);
    float r1 = fmaxf(d1 * rs * gv0.y + bev0.y, 0.f);
    float r2 = fmaxf(d2 * rs * gv0.z + bev0.z, 0.f);
    float r3 = fmaxf(d3 * rs * gv0.w + bev0.w, 0.f);
    float r4 = fmaxf(d4 * rs * gv1.x + bev1.x, 0.f);
    float r5 = fmaxf(d5 * rs * gv1.y + bev1.y, 0.f);
    float r6 = fmaxf(d6 * rs * gv1.z + bev1.z, 0.f);
    float r7 = fmaxf(d7 * rs * gv1.w + bev1.w, 0.f);
    if (flags[0]) {
        float4* o = (float4*)outAny + (size_t)node * 32 + 2 * l16;
        o[0] = make_float4(r0, r1, r2, r3);
        o[1] = make_float4(r4, r5, r6, r7);
    } else {
        uint4 o;
        o.x = pk2(r0, r1); o.y = pk2(r2, r3);
        o.z = pk2(r4, r5); o.w = pk2(r6, r7);
        ((uint4*)outAny)[(size_t)node * 16 + l16] = o;
    }
}

extern "C" void kernel_launch(void* const* d_in, const int* in_sizes, int n_in,
                              void* d_out, int out_size, void* d_ws, size_t ws_size,
                              hipStream_t stream) {
    const unsigned short* x_u16 = (const unsigned short*)d_in[0];
    const int*            ei    = (const int*)d_in[1];

    const int N = in_sizes[0] / 128;
    const int E = in_sizes[2];
    const int B = (N + 255) >> 8;          // buckets of 256 nodes (<=256)
    const int chunk = (E + G1 - 1) / G1;

    // ---- workspace layout ----
    unsigned short* Hh2 = (unsigned short*)d_ws;           // N*128 f16
    unsigned short* Hh  = Hh2 + (size_t)N * 128;           // N*128 f16
    unsigned int* gA    = (unsigned int*)(Hh + (size_t)N * 128); // E
    unsigned int* edata = gA + E;                          // B*CAPB
    unsigned char* g8   = (unsigned char*)(edata + (size_t)B * CAPB); // E (pad 4)
    int* cnt2d  = (int*)(g8 + ((E + 3) & ~3));             // 256*256
    int* lofs2d = cnt2d + 65536;                           // 256*256
    uint2* nfo  = (uint2*)(lofs2d + 65536);                // N
    int* flags  = (int*)(nfo + N);                         // 8
    unsigned short* Wt1 = (unsigned short*)(flags + 8);    // 16384 bf16
    unsigned short* Wt2 = Wt1 + 16384;                     // 16384 bf16
    float* sm   = (float*)(Wt2 + 16384);                   // 6*128 f32
    float* b1f  = sm;
    float* b2f_ = sm + 128;
    float* g1f  = sm + 256;
    float* g2f  = sm + 384;
    float* be1f = sm + 512;
    float* be2f = sm + 640;

    const int nodeBlocks = (N + 15) / 16;
    const int gemmBlocks = (N + 63) / 64;

    // ---- pass1: edge binning + weight prep (merged, 320 blocks) ----
    k_p1<<<G1 + 64, 256, 0, stream>>>(x_u16, ei, d_in[2],
                                      d_in[3], d_in[5], d_in[4], d_in[6],
                                      d_in[7], d_in[9], d_in[8], d_in[10],
                                      Wt1, Wt2, sm,
                                      E, B, chunk, gA, g8, cnt2d, lofs2d, flags);

    // ---- pass3 CSR finalize + layer-1 GEMM (merged, independent roles) ----
    k_p3g<<<B + gemmBlocks, 256, 0, stream>>>(gA, g8, cnt2d, lofs2d, edata, nfo,
                                              d_in[0], Wt1, Hh, flags, N, B, chunk);

    // ---- layer-1 aggregate + LN + ReLU + layer-2 GEMM (fused) ----
    k_agg_gemm<<<nodeBlocks, 256, 0, stream>>>(Hh, edata, nfo, b1f, g1f, be1f,
                                               Wt2, Hh2, N);

    // ---- layer-2 aggregate + LN + ReLU -> d_out ----
    k_agg_ln<<<nodeBlocks, 256, 0, stream>>>(Hh2, edata, nfo, b2f_, g2f, be2f,
                                             d_out, flags, N);
}